// Round 16
// baseline (281.124 us; speedup 1.0000x reference)
//
#include <hip/hip_runtime.h>

#define NBATCH 8
#define NR     16          // vertex ranges per batch -> bins = NBATCH*NR = 128
#define TA     256         // phase-A block size (tile = TA faces)
#define SEGA   128         // phase-A segments per batch -> 1024 blocks
#define RANGE_BIG 13312    // fallback fused-gather tile (r9, measured 104 us)

struct I3 { int a, b, c; };
struct P3 { float x, y, z; };

// ---------------------------------------------------------------------------
// Cotangent weights per the reference (Heron, EPS guard, A==0 -> 0).
// ---------------------------------------------------------------------------
__device__ __forceinline__ void cot_weights(
    const P3& p0, const P3& p1, const P3& p2,
    float& w0, float& w1, float& w2)
{
    const float EPSf = 1e-10f;
    float dx, dy, dz;
    dx = p1.x - p2.x; dy = p1.y - p2.y; dz = p1.z - p2.z;
    float l1 = sqrtf(dx * dx + dy * dy + dz * dz);
    dx = p2.x - p0.x; dy = p2.y - p0.y; dz = p2.z - p0.z;
    float l2 = sqrtf(dx * dx + dy * dy + dz * dz);
    dx = p0.x - p1.x; dy = p0.y - p1.y; dz = p0.z - p1.z;
    float l3 = sqrtf(dx * dx + dy * dy + dz * dz);

    float sp = (l1 + l2 + l3) * 0.5f;
    float inside = sp * (sp - l1) * (sp - l2) * (sp - l3);
    inside = fmaxf(inside, 0.0f);
    float A = 2.0f * sqrtf(inside);
    float denom = A + EPSf;

    float l1s = l1 * l1, l2s = l2 * l2, l3s = l3 * l3;
    w0 = (l2s + l3s - l1s) / denom * 0.25f;
    w1 = (l1s + l3s - l2s) / denom * 0.25f;
    w2 = (l1s + l2s - l3s) / denom * 0.25f;
    if (A == 0.0f) { w0 = 0.0f; w1 = 0.0f; w2 = 0.0f; }
}

__device__ __forceinline__ void face_contrib(
    const P3& p0, const P3& p1, const P3& p2, float* c)
{
    float w0, w1, w2;
    cot_weights(p0, p1, p2, w0, w1, w2);
    c[0] = w1 * (p2.x - p0.x) + w2 * (p1.x - p0.x);
    c[1] = w1 * (p2.y - p0.y) + w2 * (p1.y - p0.y);
    c[2] = w1 * (p2.z - p0.z) + w2 * (p1.z - p0.z);
    c[3] = w0 * (p2.x - p1.x) + w2 * (p0.x - p1.x);
    c[4] = w0 * (p2.y - p1.y) + w2 * (p0.y - p1.y);
    c[5] = w0 * (p2.z - p1.z) + w2 * (p0.z - p1.z);
    c[6] = w0 * (p1.x - p2.x) + w1 * (p0.x - p2.x);
    c[7] = w0 * (p1.y - p2.y) + w1 * (p0.y - p2.y);
    c[8] = w0 * (p1.z - p2.z) + w1 * (p0.z - p2.z);
}

// ---------------------------------------------------------------------------
// Phase A: visit each face ONCE; compute 3 corner records; bin them by
// (batch, vertex/range) with block-level LDS staging + one global counter
// atomic per bin per tile. Record = {cx, cy, cz, bitcast(local_v)}.
// ---------------------------------------------------------------------------
__global__ void __launch_bounds__(TA) cot_binA(
    const float* __restrict__ V, const int* __restrict__ F,
    float4* __restrict__ bins, int* __restrict__ counters,
    int N, int Fc, int range, int cap)
{
    __shared__ int    lcnt[NR];
    __shared__ int    loff[NR];
    __shared__ int    lcur[NR];
    __shared__ int    gbase[NR];
    __shared__ float4 stage[TA * 3];

    int b = blockIdx.x / SEGA;
    int s = blockIdx.x % SEGA;
    int fps = (Fc + SEGA - 1) / SEGA;
    int f0 = s * fps;
    int f1 = min(f0 + fps, Fc);
    if (f0 >= f1) return;

    const int*   Fb = F + (size_t)b * Fc * 3;
    const float* Vb = V + (size_t)b * N * 3;

    for (int base = f0; base < f1; base += TA) {
        int f = base + (int)threadIdx.x;
        bool valid = f < f1;

        if (threadIdx.x < NR) lcnt[threadIdx.x] = 0;
        __syncthreads();

        I3 ix = {0, 0, 0};
        int r0 = 0, r1 = 0, r2 = 0;
        if (valid) {
            ix = *reinterpret_cast<const I3*>(Fb + (size_t)f * 3);
            r0 = ix.a / range; r1 = ix.b / range; r2 = ix.c / range;
            atomicAdd(&lcnt[r0], 1);
            atomicAdd(&lcnt[r1], 1);
            atomicAdd(&lcnt[r2], 1);
        }
        __syncthreads();

        if (threadIdx.x == 0) {
            int acc = 0;
#pragma unroll
            for (int r = 0; r < NR; ++r) { loff[r] = acc; lcur[r] = acc; acc += lcnt[r]; }
        }
        __syncthreads();

        if (valid) {
            P3 p0 = *reinterpret_cast<const P3*>(Vb + (size_t)ix.a * 3);
            P3 p1 = *reinterpret_cast<const P3*>(Vb + (size_t)ix.b * 3);
            P3 p2 = *reinterpret_cast<const P3*>(Vb + (size_t)ix.c * 3);
            float c[9];
            face_contrib(p0, p1, p2, c);

            unsigned w0p = (unsigned)(ix.a - r0 * range) | ((unsigned)r0 << 20);
            unsigned w1p = (unsigned)(ix.b - r1 * range) | ((unsigned)r1 << 20);
            unsigned w2p = (unsigned)(ix.c - r2 * range) | ((unsigned)r2 << 20);

            int q0 = atomicAdd(&lcur[r0], 1);
            stage[q0] = make_float4(c[0], c[1], c[2], __uint_as_float(w0p));
            int q1 = atomicAdd(&lcur[r1], 1);
            stage[q1] = make_float4(c[3], c[4], c[5], __uint_as_float(w1p));
            int q2 = atomicAdd(&lcur[r2], 1);
            stage[q2] = make_float4(c[6], c[7], c[8], __uint_as_float(w2p));
        }
        __syncthreads();

        if (threadIdx.x < NR) {
            int c = lcnt[threadIdx.x];
            gbase[threadIdx.x] = (c > 0)
                ? atomicAdd(&counters[b * NR + (int)threadIdx.x], c) : 0;
        }
        __syncthreads();

        int tot = loff[NR - 1] + lcnt[NR - 1];
        for (int i = threadIdx.x; i < tot; i += TA) {
            float4 rec = stage[i];
            unsigned w = __float_as_uint(rec.w);
            int r = (int)(w >> 20);
            int v = (int)(w & 0xFFFFFu);
            int dst = gbase[r] + (i - loff[r]);
            if (dst < cap) {
                rec.w = __uint_as_float((unsigned)v);
                bins[((size_t)(b * NR + r)) * cap + dst] = rec;
            }
        }
        __syncthreads();   // protect stage/lcnt before next tile
    }
}

// ---------------------------------------------------------------------------
// Phase B: one block per bin. Stream the bin's records coalesced, ds_add
// into the LDS tile, write the tile. Full output coverage -> no merge.
// ---------------------------------------------------------------------------
__global__ void __launch_bounds__(1024) cot_binB(
    const float4* __restrict__ bins, const int* __restrict__ counters,
    float* __restrict__ out, int N, int range, int cap)
{
    extern __shared__ float lacc[];
    int bin = blockIdx.x;
    int b = bin / NR, r = bin % NR;
    int lo = r * range;
    int hi = min(lo + range, N);
    if (lo >= N) return;
    int len3 = (hi - lo) * 3;

    for (int i = threadIdx.x; i < len3; i += 1024) lacc[i] = 0.0f;
    __syncthreads();

    int cnt = counters[bin];
    if (cnt > cap) cnt = cap;
    const float4* mb = bins + (size_t)bin * cap;

    for (int i = threadIdx.x; i < cnt; i += 1024) {
        float4 rec = mb[i];
        int v = (int)__float_as_uint(rec.w);
        atomicAdd(&lacc[v * 3 + 0], rec.x);
        atomicAdd(&lacc[v * 3 + 1], rec.y);
        atomicAdd(&lacc[v * 3 + 2], rec.z);
    }
    __syncthreads();

    float* dst = out + ((size_t)b * N + lo) * 3;
    for (int i = threadIdx.x; i < len3; i += 1024) dst[i] = lacc[i];
}

// ---------------------------------------------------------------------------
// Fallback 1: round-9 fused gather (measured 104 us) + merge.
// ---------------------------------------------------------------------------
__global__ void __launch_bounds__(1024, 1) cot_gather_big(
    const float* __restrict__ V, const int* __restrict__ F,
    float* __restrict__ part, int N, int Fc, int BN3, int nseg)
{
    extern __shared__ float lacc[];
    int nr = (N + RANGE_BIG - 1) / RANGE_BIG;

    int b = blockIdx.x % NBATCH;
    int t = blockIdx.x / NBATCH;
    int r = t / nseg;
    int s = t % nseg;
    if (r >= nr) return;

    int lo = r * RANGE_BIG;
    int hi = min(lo + RANGE_BIG, N);
    unsigned rlen = (unsigned)(hi - lo);
    int len3 = (hi - lo) * 3;

    for (int i = threadIdx.x; i < len3; i += 1024) lacc[i] = 0.0f;
    __syncthreads();

    int fps = (Fc + nseg - 1) / nseg;
    int f0 = s * fps;
    int f1 = min(f0 + fps, Fc);

    const int*   Fb = F + (size_t)b * Fc * 3;
    const float* Vb = V + (size_t)b * N * 3;

    for (int f = f0 + (int)threadIdx.x; f < f1; f += 1024) {
        I3 ix = *reinterpret_cast<const I3*>(Fb + (size_t)f * 3);
        unsigned u0 = (unsigned)(ix.a - lo);
        unsigned u1 = (unsigned)(ix.b - lo);
        unsigned u2 = (unsigned)(ix.c - lo);
        bool in0 = u0 < rlen, in1 = u1 < rlen, in2 = u2 < rlen;
        if (!(in0 || in1 || in2)) continue;

        P3 p0 = *reinterpret_cast<const P3*>(Vb + (size_t)ix.a * 3);
        P3 p1 = *reinterpret_cast<const P3*>(Vb + (size_t)ix.b * 3);
        P3 p2 = *reinterpret_cast<const P3*>(Vb + (size_t)ix.c * 3);

        float c[9];
        face_contrib(p0, p1, p2, c);

        if (in0) {
            atomicAdd(&lacc[u0 * 3 + 0], c[0]);
            atomicAdd(&lacc[u0 * 3 + 1], c[1]);
            atomicAdd(&lacc[u0 * 3 + 2], c[2]);
        }
        if (in1) {
            atomicAdd(&lacc[u1 * 3 + 0], c[3]);
            atomicAdd(&lacc[u1 * 3 + 1], c[4]);
            atomicAdd(&lacc[u1 * 3 + 2], c[5]);
        }
        if (in2) {
            atomicAdd(&lacc[u2 * 3 + 0], c[6]);
            atomicAdd(&lacc[u2 * 3 + 1], c[7]);
            atomicAdd(&lacc[u2 * 3 + 2], c[8]);
        }
    }
    __syncthreads();

    float* dst = part + (size_t)s * BN3 + ((size_t)b * N + lo) * 3;
    for (int i = threadIdx.x; i < len3; i += 1024) dst[i] = lacc[i];
}

__global__ void __launch_bounds__(256) cot_merge4(
    const float* __restrict__ part, float* __restrict__ out, int BN3, int nseg)
{
    int i = blockIdx.x * blockDim.x + threadIdx.x;
    int n4 = BN3 >> 2;
    if (i >= n4) return;
    float4 a = ((const float4*)part)[i];
    for (int s = 1; s < nseg; ++s) {
        float4 p = ((const float4*)(part + (size_t)s * BN3))[i];
        a.x += p.x; a.y += p.y; a.z += p.z; a.w += p.w;
    }
    ((float4*)out)[i] = a;
}

__global__ void __launch_bounds__(256) cot_merge1(
    const float* __restrict__ part, float* __restrict__ out, int BN3, int nseg)
{
    int i = blockIdx.x * blockDim.x + threadIdx.x;
    if (i >= BN3) return;
    float v = part[i];
    for (int s = 1; s < nseg; ++s) v += part[(size_t)s * BN3 + i];
    out[i] = v;
}

// Fallback 2: direct device-scope atomics.
__global__ void __launch_bounds__(256) cot_face_add9(
    const float* __restrict__ V, const int* __restrict__ F,
    float* __restrict__ out, int N, int Fc)
{
    int idx = blockIdx.x * blockDim.x + threadIdx.x;
    int total = NBATCH * Fc;
    if (idx >= total) return;

    int b = idx / Fc;
    I3 ix = *reinterpret_cast<const I3*>(F + (size_t)idx * 3);
    int vb = b * N;
    int g0 = vb + ix.a, g1 = vb + ix.b, g2 = vb + ix.c;

    P3 p0 = *reinterpret_cast<const P3*>(V + (size_t)g0 * 3);
    P3 p1 = *reinterpret_cast<const P3*>(V + (size_t)g1 * 3);
    P3 p2 = *reinterpret_cast<const P3*>(V + (size_t)g2 * 3);

    float c[9];
    face_contrib(p0, p1, p2, c);

    atomicAdd(&out[(size_t)g0 * 3 + 0], c[0]);
    atomicAdd(&out[(size_t)g0 * 3 + 1], c[1]);
    atomicAdd(&out[(size_t)g0 * 3 + 2], c[2]);
    atomicAdd(&out[(size_t)g1 * 3 + 0], c[3]);
    atomicAdd(&out[(size_t)g1 * 3 + 1], c[4]);
    atomicAdd(&out[(size_t)g1 * 3 + 2], c[5]);
    atomicAdd(&out[(size_t)g2 * 3 + 0], c[6]);
    atomicAdd(&out[(size_t)g2 * 3 + 1], c[7]);
    atomicAdd(&out[(size_t)g2 * 3 + 2], c[8]);
}

extern "C" void kernel_launch(void* const* d_in, const int* in_sizes, int n_in,
                              void* d_out, int out_size, void* d_ws, size_t ws_size,
                              hipStream_t stream) {
    const float* V = (const float*)d_in[0];
    const int*   F = (const int*)d_in[1];
    float* out = (float*)d_out;

    int BN3 = in_sizes[0];
    int N   = BN3 / (NBATCH * 3);
    int Fc  = in_sizes[1] / (NBATCH * 3);
    int totalF = NBATCH * Fc;

    // ---------------- binning path ----------------
    int range = (N + NR - 1) / NR;                       // 6250 at N=100k
    size_t ldsB = (size_t)range * 3 * sizeof(float);     // 75000 B
    int nbins = NBATCH * NR;
    size_t cap_fit = (ws_size > 4096)
                   ? (ws_size - 4096) / ((size_t)nbins * sizeof(float4)) : 0;
    size_t mean_per_bin = ((size_t)3 * Fc + NR - 1) / NR;
    size_t cap_min = mean_per_bin + mean_per_bin / 7 + 64;   // ~1.14x + slack
    size_t cap_cl  = cap_fit;
    if (cap_cl > 4 * cap_min) cap_cl = 4 * cap_min;          // keep int-sized

    if (cap_fit >= cap_min && ldsB <= 163840 && range < (1 << 20) &&
        hipFuncSetAttribute(reinterpret_cast<const void*>(cot_binB),
                            hipFuncAttributeMaxDynamicSharedMemorySize,
                            (int)ldsB) == hipSuccess) {
        int cap = (int)cap_cl;
        float4* bins = (float4*)d_ws;
        int* counters = (int*)((char*)d_ws + (size_t)nbins * cap * sizeof(float4));

        hipMemsetAsync(counters, 0, (size_t)nbins * sizeof(int), stream);
        cot_binA<<<NBATCH * SEGA, TA, 0, stream>>>(V, F, bins, counters, N, Fc, range, cap);
        cot_binB<<<nbins, 1024, (int)ldsB, stream>>>(bins, counters, out, N, range, cap);
        return;
    }

    // ---------------- fallback 1: r9 fused gather ----------------
    size_t pbytes = (size_t)BN3 * sizeof(float);
    const int dynLds = RANGE_BIG * 3 * sizeof(float);
    int nrG = (N + RANGE_BIG - 1) / RANGE_BIG;
    if (ws_size >= 4 * pbytes &&
        hipFuncSetAttribute(reinterpret_cast<const void*>(cot_gather_big),
                            hipFuncAttributeMaxDynamicSharedMemorySize,
                            dynLds) == hipSuccess) {
        int fseg = 4;
        int gblocks = NBATCH * nrG * fseg;
        cot_gather_big<<<gblocks, 1024, dynLds, stream>>>(V, F, (float*)d_ws, N, Fc, BN3, fseg);
        if ((BN3 & 3) == 0) {
            int mblocks = ((BN3 >> 2) + 255) / 256;
            cot_merge4<<<mblocks, 256, 0, stream>>>((const float*)d_ws, out, BN3, fseg);
        } else {
            int mblocks = (BN3 + 255) / 256;
            cot_merge1<<<mblocks, 256, 0, stream>>>((const float*)d_ws, out, BN3, fseg);
        }
        return;
    }

    // ---------------- fallback 2 ----------------
    hipMemsetAsync(d_out, 0, (size_t)BN3 * sizeof(float), stream);
    int fblocks = (totalF + 255) / 256;
    cot_face_add9<<<fblocks, 256, 0, stream>>>(V, F, out, N, Fc);
}